// Round 21
// baseline (371.687 us; speedup 1.0000x reference)
//
#include <hip/hip_runtime.h>

#define B_ 16
#define C_ 256
#define NH_ 8
#define DK_ 32
#define DV_ 64
#define S_ 1024
#define CV_ 512

typedef __bf16 bf16;
typedef bf16 bf16x4 __attribute__((ext_vector_type(4)));
typedef bf16 bf16x8 __attribute__((ext_vector_type(8)));
typedef float f32x4 __attribute__((ext_vector_type(4)));

constexpr float EPSV = 1e-5f;
constexpr float SCALE_ = 0.17677669529663687f;   // 32^-0.5
constexpr float LOG2E_ = 1.4426950408889634f;
constexpr float QSCALE_ = SCALE_ * LOG2E_;       // folded into Q weights
constexpr float BSCALE_ = (1.0f / SCALE_) * LOG2E_; // folded into bias table

// ---------------- prep: fold BN into weights, cast to bf16 ----------------
__global__ void prep_kernel(const float* __restrict__ Wq, const float* __restrict__ qg, const float* __restrict__ qb, const float* __restrict__ qm, const float* __restrict__ qv,
                            const float* __restrict__ Wk, const float* __restrict__ kg, const float* __restrict__ kb, const float* __restrict__ km, const float* __restrict__ kv,
                            const float* __restrict__ Wv, const float* __restrict__ vg, const float* __restrict__ vb, const float* __restrict__ vm, const float* __restrict__ vv,
                            const float* __restrict__ Wo, const float* __restrict__ bo, const float* __restrict__ og_, const float* __restrict__ ob_, const float* __restrict__ om_, const float* __restrict__ ov_,
                            bf16* __restrict__ wqkv, float* __restrict__ bqkv, bf16* __restrict__ wo2, float* __restrict__ bo2) {
  int idx = blockIdx.x * 256 + threadIdx.x;
  if (idx < 1024 * 256) {
    int o = idx >> 8, c = idx & 255;
    float w, g, v;
    if (o < 256)      { w = Wq[o * 256 + c];        g = qg[o];       v = qv[o]; }
    else if (o < 512) { w = Wk[(o - 256) * 256 + c]; g = kg[o - 256]; v = kv[o - 256]; }
    else              { w = Wv[(o - 512) * 256 + c]; g = vg[o - 512]; v = vv[o - 512]; }
    float inv = g * rsqrtf(v + EPSV);
    wqkv[idx] = (bf16)(w * inv);
    if (c == 0) {
      float bb, m;
      if (o < 256)      { bb = qb[o];       m = qm[o]; }
      else if (o < 512) { bb = kb[o - 256]; m = km[o - 256]; }
      else              { bb = vb[o - 512]; m = vm[o - 512]; }
      bqkv[o] = bb - m * inv;
    }
  } else {
    int j = idx - 1024 * 256;
    if (j < 256 * 512) {
      int co = j >> 9, cv = j & 511;
      float inv = og_[co] * rsqrtf(ov_[co] + EPSV);
      wo2[j] = (bf16)(Wo[j] * inv);
      if (cv == 0) bo2[co] = bo[co] * inv + ob_[co] - om_[co] * inv;
    }
  }
}

// ---------------- transpose x[b,c,s] f32 -> xT[b,s,c] bf16 (vectorized) ----------------
__global__ __launch_bounds__(256) void xpose_kernel(const float* __restrict__ x, bf16* __restrict__ xT) {
  __shared__ bf16 t[64][66];
  int b = blockIdx.z, c0 = blockIdx.y * 64, s0 = blockIdx.x * 64;
  const float* xp = x + ((size_t)b * C_ + c0) * S_ + s0;
#pragma unroll
  for (int p = 0; p < 4; ++p) {
    int q = p * 256 + threadIdx.x;          // 0..1023 quads
    int ci = q >> 4, si4 = (q & 15) * 4;
    float4 v = *(const float4*)(xp + (size_t)ci * S_ + si4);
    t[si4 + 0][ci] = (bf16)v.x;
    t[si4 + 1][ci] = (bf16)v.y;
    t[si4 + 2][ci] = (bf16)v.z;
    t[si4 + 3][ci] = (bf16)v.w;
  }
  __syncthreads();
  bf16* op = xT + ((size_t)b * S_ + s0) * C_ + c0;
#pragma unroll
  for (int p = 0; p < 4; ++p) {
    int q = p * 256 + threadIdx.x;
    int si = q >> 4, ci4 = (q & 15) * 4;
    bf16x4 pk;
#pragma unroll
    for (int e = 0; e < 4; ++e) pk[e] = t[si][ci4 + e];
    *(bf16x4*)(op + (size_t)si * C_ + ci4) = pk;
  }
}

// ---------------- fused QKV GEMM, m97 structure (proven round 14) ----------------
__device__ __forceinline__ void gload16(const void* g, void* l) {
  __builtin_amdgcn_global_load_lds((const __attribute__((address_space(1))) void*)g,
                                   (__attribute__((address_space(3))) void*)l, 16, 0, 0);
}

__global__ __launch_bounds__(256) void qkv_gemm_kernel(const bf16* __restrict__ wqkv, const float* __restrict__ bqkv,
                                                       const bf16* __restrict__ xT, bf16* __restrict__ qh,
                                                       bf16* __restrict__ kh, bf16* __restrict__ vT) {
  __shared__ bf16 alds[2][128 * 32];
  __shared__ bf16 blds[2][128 * 32];
  const int b = blockIdx.z;
  const int ob = blockIdx.y * 128, sb = blockIdx.x * 128;
  const int w = threadIdx.x >> 6, lane = threadIdx.x & 63;
  const int g = lane >> 4, lo = lane & 15;
  const int ow = (w >> 1) * 64, sw = (w & 1) * 64;

  const int r0 = threadIdx.x >> 2, c4 = threadIdx.x & 3;
  const int swz = (c4 ^ ((r0 >> 1) & 3)) * 8;
  const bf16* aS = wqkv + (size_t)(ob + r0) * C_ + swz;
  const bf16* bS = xT + ((size_t)b * S_ + sb + r0) * C_ + swz;
  const int ldst = threadIdx.x * 8;
  auto stage = [&](int buf, int kc) {
    gload16(aS + kc, &alds[buf][ldst]);
    gload16(aS + (size_t)64 * C_ + kc, &alds[buf][ldst + 2048]);
    gload16(bS + kc, &blds[buf][ldst]);
    gload16(bS + (size_t)64 * C_ + kc, &blds[buf][ldst + 2048]);
  };

  f32x4 acc[4][4] = {};

  stage(0, 0);
  __syncthreads();

  for (int step = 0; step < 8; ++step) {
    const int cur = step & 1;
    if (step < 7) stage(cur ^ 1, (step + 1) * 32);
    bf16x8 af[4], bfr[4];
    const int ch = (g ^ ((lo >> 1) & 3)) * 8;
#pragma unroll
    for (int i = 0; i < 4; ++i)
      af[i] = *(const bf16x8*)(&alds[cur][(ow + i * 16 + lo) * 32 + ch]);
#pragma unroll
    for (int j = 0; j < 4; ++j)
      bfr[j] = *(const bf16x8*)(&blds[cur][(sw + j * 16 + lo) * 32 + ch]);
#pragma unroll
    for (int i = 0; i < 4; ++i)
#pragma unroll
      for (int j = 0; j < 4; ++j)
        acc[i][j] = __builtin_amdgcn_mfma_f32_16x16x32_bf16(af[i], bfr[j], acc[i][j], 0, 0, 0);
    __syncthreads();
  }

#pragma unroll
  for (int i = 0; i < 4; ++i) {
    const int o0 = ob + ow + i * 16 + 4 * g;
    const bool isv = o0 >= 512;
    const bool isq = o0 < 256;
    float bias4[4];
#pragma unroll
    for (int r = 0; r < 4; ++r) bias4[r] = bqkv[o0 + r];
#pragma unroll
    for (int j = 0; j < 4; ++j) {
      const int s = sb + sw + j * 16 + lo;
      if (!isv) {
        const int n = (o0 >> 5) & 7;
        const int d0 = o0 & 31;
        bf16x4 pk;
#pragma unroll
        for (int r = 0; r < 4; ++r) {
          float v = acc[i][j][r] + bias4[r];
          pk[r] = (bf16)(isq ? v * QSCALE_ : v);
        }
        bf16* dst = (isq ? qh : kh) + (((size_t)b * NH_ + n) * S_ + s) * DK_ + d0;
        *(bf16x4*)dst = pk;
      } else {
        const int o2 = o0 - 512;
        const int n = o2 >> 6, dv0 = o2 & 63;
#pragma unroll
        for (int r = 0; r < 4; ++r)
          vT[(((size_t)b * NH_ + n) * DV_ + dv0 + r) * S_ + s] = (bf16)(acc[i][j][r] + bias4[r]);
      }
    }
  }
}

// ---------------- flash attention: r14 structure, slim wave state (no lac/ones) ----------------
// 8 waves x 32 q, KVBLK=64 (proven fragment/swizzle math). Changes vs the 47.9us r20:
// (a) row-sum l via 2 scalar f32 accumulators (each lane's 16 p-values are k-slices
//     of ITS OWN q-column in the swapped layout) + ONE epilogue shfl_xor(16/32)
//     reduce over g-groups (round-1 proven). Deletes lac[2] (16 VGPR) + ones (4).
// (b) bias quad table in bf16 (16 KB, r17/r18-proven absmax-neutral), quads read
//     lazily per-u (short-lived cvt temps - r19 pre-converted 24 floats and spilled).
// -> LDS = 16+8+16 = 40960 B (4 blocks x 40960 = exactly 160 KB) and VGPR ~55 <= 64
// -> __launch_bounds__(512,8): 32 waves/CU, 2x TLP for the ~30% latency idle.
// Spill gate: VGPR_Count=32 + WRITE blowup = fail -> revert.
__global__ __launch_bounds__(512, 8) void attn_kernel(const bf16* __restrict__ qh, const bf16* __restrict__ kh,
                                                      const bf16* __restrict__ vT, const float* __restrict__ pos_emb,
                                                      bf16* __restrict__ og) {
  __shared__ __align__(16) bf16 E4b[32 * 64 * 4];   // 16384 B
  __shared__ bf16 klds[2][64 * 32];                 // 8192 B
  __shared__ bf16 vlds[2][64 * 64];                 // 16384 B
  const int n = blockIdx.x, qt = blockIdx.y, b = blockIdx.z;
  const int w = threadIdx.x >> 6, lane = threadIdx.x & 63;
  const int g = lane >> 4, lo = lane & 15;
  const size_t bn = (size_t)b * NH_ + n;
  const bf16* __restrict__ kbase = kh + bn * (size_t)S_ * DK_;
  const bf16* __restrict__ vbase = vT + bn * (size_t)DV_ * S_;

  const int krow = (w & 3) * 16 + (lane >> 2), kslot = lane & 3;
  const int vrow = w * 8 + (lane >> 3), vslot = lane & 7;
  const bf16* ksrc0 = kbase + (size_t)krow * DK_ + ((kslot ^ ((krow >> 2) & 3)) * 8);
  const bf16* vsrc0 = vbase + (size_t)vrow * S_ + ((vslot ^ (vrow & 7)) * 8);
  auto stage = [&](int buf, int kt) {
    if (w < 4) gload16(ksrc0 + (size_t)kt * DK_, &klds[buf][(w & 3) * 512]);
    gload16(vsrc0 + kt, &vlds[buf][w * 512]);
  };

  stage(0, 0);

  // bf16 bias quad table: E4b[dr][d][j] = pos[(dr*32 + clamp(|d-28-j|))*NH + n]*BSCALE
  for (int i = threadIdx.x; i < 2048; i += 512) {
    const int dr = i >> 6, d = i & 63;
    bf16x4 v;
#pragma unroll
    for (int j = 0; j < 4; ++j) {
      int dc = d - 28 - j;
      dc = dc < 0 ? -dc : dc;
      dc = dc > 31 ? 31 : dc;
      v[j] = (bf16)(pos_emb[(dr * 32 + dc) * NH_ + n] * BSCALE_);
    }
    *(bf16x4*)(E4b + (size_t)i * 4) = v;
  }

  const int qbase = qt * 256 + w * 32;
  const int q0 = qbase + lo, q1 = qbase + 16 + lo;
  const bf16x8 qf0 = *(const bf16x8*)(qh + (bn * S_ + q0) * DK_ + 8 * g);
  const bf16x8 qf1 = *(const bf16x8*)(qh + (bn * S_ + q1) * DK_ + 8 * g);
  const int qr = qbase >> 5;
  const bf16* Qb = E4b + (12 + lo - 4 * g) * 4;

  f32x4 acc[4][2] = {};
  float lr0 = 0.f, lr1 = 0.f;

  asm volatile("s_waitcnt vmcnt(0)" ::: "memory");
  __syncthreads();

  for (int it = 0; it < 16; ++it) {
    const int kt = it * 64;
    const int cur = it & 1;
    if (it < 15) stage(cur ^ 1, kt + 64);
    const bf16* kbuf = &klds[cur][0];
    const bf16* vbuf = &vlds[cur][0];

    int dq = qr - 2 * it;
    int dra = dq < 0 ? -dq : dq;
    int dqb = dq - 1;
    int drb = dqb < 0 ? -dqb : dqb;
    const bf16* QA = Qb + dra * 256;
    const bf16* QP = Qb + drb * 256;

    // ---- QK^T with bias in C-operand; exp2 -> PV B-fragments + scalar l-sums ----
    bf16x8 pb[2][2];  // [q-half][key-half]
#pragma unroll
    for (int u = 0; u < 4; ++u) {
      const int row = u * 16 + lo;
      bf16x8 ka = *(const bf16x8*)(kbuf + row * 32 + ((8 * g) ^ (((row >> 2) & 3) << 3)));
      bf16x4 c0b, c1b;
      if (u == 0)      { c0b = *(const bf16x4*)(QA + 64);  c1b = *(const bf16x4*)(QA + 128); }
      else if (u == 1) { c0b = *(const bf16x4*)(QA);       c1b = *(const bf16x4*)(QA + 64); }
      else if (u == 2) { c0b = *(const bf16x4*)(QP + 64);  c1b = *(const bf16x4*)(QP + 128); }
      else             { c0b = *(const bf16x4*)(QP);       c1b = *(const bf16x4*)(QP + 64); }
      f32x4 c0, c1;
#pragma unroll
      for (int e = 0; e < 4; ++e) { c0[e] = (float)c0b[e]; c1[e] = (float)c1b[e]; }
      f32x4 s0 = __builtin_amdgcn_mfma_f32_16x16x32_bf16(ka, qf0, c0, 0, 0, 0);
      f32x4 s1 = __builtin_amdgcn_mfma_f32_16x16x32_bf16(ka, qf1, c1, 0, 0, 0);
      const int cb = (u & 1) * 4;
      const int up = u >> 1;
#pragma unroll
      for (int r = 0; r < 4; ++r) {
        float p0 = __builtin_amdgcn_exp2f(s0[r]);
        float p1 = __builtin_amdgcn_exp2f(s1[r]);
        lr0 += p0;
        lr1 += p1;
        pb[0][up][cb + r] = (bf16)p0;
        pb[1][up][cb + r] = (bf16)p1;
      }
    }

    __builtin_amdgcn_s_setprio(1);
    // ---- PV: acc[t][h] += V_frag . P[h] (V reads shared across both q-halves) ----
#pragma unroll
    for (int t = 0; t < 4; ++t) {
      const int row = t * 16 + lo;
      const int rsw = row & 7;
      const bf16* vrow_p = vbuf + row * 64 + 4 * (g & 1);
      const int ghalf = g >> 1;
#pragma unroll
      for (int up = 0; up < 2; ++up) {
        bf16x4 va0 = *(const bf16x4*)(vrow_p + ((((4 * up + 0) + ghalf) ^ rsw) << 3));
        bf16x4 va1 = *(const bf16x4*)(vrow_p + ((((4 * up + 2) + ghalf) ^ rsw) << 3));
        bf16x8 va = __builtin_shufflevector(va0, va1, 0, 1, 2, 3, 4, 5, 6, 7);
        acc[t][0] = __builtin_amdgcn_mfma_f32_16x16x32_bf16(va, pb[0][up], acc[t][0], 0, 0, 0);
        acc[t][1] = __builtin_amdgcn_mfma_f32_16x16x32_bf16(va, pb[1][up], acc[t][1], 0, 0, 0);
      }
    }
    __builtin_amdgcn_s_setprio(0);

    asm volatile("s_waitcnt vmcnt(0)" ::: "memory");
    __syncthreads();
  }

  // ---- epilogue: cross-g reduce of l (lanes lo, lo+16, lo+32, lo+48 share a q-col) ----
  lr0 += __shfl_xor(lr0, 16, 64);
  lr0 += __shfl_xor(lr0, 32, 64);
  lr1 += __shfl_xor(lr1, 16, 64);
  lr1 += __shfl_xor(lr1, 32, 64);

#pragma unroll
  for (int h = 0; h < 2; ++h) {
    const float rinv = __builtin_amdgcn_rcpf(h == 0 ? lr0 : lr1);
    const int qx = qbase + 16 * h + lo;
    bf16* op = og + ((size_t)b * S_ + qx) * CV_ + n * DV_;
#pragma unroll
    for (int t = 0; t < 4; ++t) {
      bf16x4 pk;
#pragma unroll
      for (int r = 0; r < 4; ++r) {
        float xo = acc[t][h][r] * rinv;
        pk[r] = (bf16)(0.5f * xo * (1.f + erff(xo * 0.70710678118654752f)));
      }
      *(bf16x4*)(op + t * 16 + 4 * g) = pk;
    }
  }
}

// ---------------- output GEMM, m97 structure (proven round 15) ----------------
__global__ __launch_bounds__(256) void out_gemm_kernel(const bf16* __restrict__ wo2, const float* __restrict__ bo2,
                                                       const bf16* __restrict__ og, float* __restrict__ out) {
  __shared__ bf16 alds[2][64 * 32];
  __shared__ bf16 blds[2][128 * 32];
  const int b = blockIdx.z;
  const int cb = blockIdx.y * 64, sb = blockIdx.x * 128;
  const int w = threadIdx.x >> 6, lane = threadIdx.x & 63;
  const int g = lane >> 4, lo = lane & 15;
  const int cw = (w >> 1) * 32, sw = (w & 1) * 64;

  const int r0 = threadIdx.x >> 2, c4 = threadIdx.x & 3;
  const int swz = (c4 ^ ((r0 >> 1) & 3)) * 8;
  const bf16* aS = wo2 + (size_t)(cb + r0) * CV_ + swz;
  const bf16* bS = og + ((size_t)b * S_ + sb + r0) * CV_ + swz;
  const int ldst = threadIdx.x * 8;
  auto stage = [&](int buf, int kc) {
    gload16(aS + kc, &alds[buf][ldst]);
    gload16(bS + kc, &blds[buf][ldst]);
    gload16(bS + (size_t)64 * CV_ + kc, &blds[buf][ldst + 2048]);
  };

  f32x4 acc[2][4] = {};

  stage(0, 0);
  __syncthreads();

  for (int step = 0; step < 16; ++step) {
    const int cur = step & 1;
    if (step < 15) stage(cur ^ 1, (step + 1) * 32);
    bf16x8 af[2], bfr[4];
    const int ch = (g ^ ((lo >> 1) & 3)) * 8;
#pragma unroll
    for (int i = 0; i < 2; ++i)
      af[i] = *(const bf16x8*)(&alds[cur][(cw + i * 16 + lo) * 32 + ch]);
#pragma unroll
    for (int j = 0; j < 4; ++j)
      bfr[j] = *(const bf16x8*)(&blds[cur][(sw + j * 16 + lo) * 32 + ch]);
#pragma unroll
    for (int i = 0; i < 2; ++i)
#pragma unroll
      for (int j = 0; j < 4; ++j)
        acc[i][j] = __builtin_amdgcn_mfma_f32_16x16x32_bf16(af[i], bfr[j], acc[i][j], 0, 0, 0);
    __syncthreads();
  }

#pragma unroll
  for (int i = 0; i < 2; ++i) {
    const int c0 = cb + cw + i * 16 + 4 * g;
    float bias4[4];
#pragma unroll
    for (int r = 0; r < 4; ++r) bias4[r] = bo2[c0 + r];
#pragma unroll
    for (int j = 0; j < 4; ++j) {
      const int s = sb + sw + j * 16 + lo;
#pragma unroll
      for (int r = 0; r < 4; ++r)
        out[((size_t)b * C_ + c0 + r) * S_ + s] = acc[i][j][r] + bias4[r];
    }
  }
}

extern "C" void kernel_launch(void* const* d_in, const int* in_sizes, int n_in,
                              void* d_out, int out_size, void* d_ws, size_t ws_size,
                              hipStream_t stream) {
  (void)in_sizes; (void)n_in; (void)out_size; (void)ws_size;
  const float* x   = (const float*)d_in[0];
  const float* Wq  = (const float*)d_in[1];
  const float* qg  = (const float*)d_in[2];
  const float* qb  = (const float*)d_in[3];
  const float* qm  = (const float*)d_in[4];
  const float* qv  = (const float*)d_in[5];
  const float* Wk  = (const float*)d_in[6];
  const float* kg  = (const float*)d_in[7];
  const float* kb  = (const float*)d_in[8];
  const float* km  = (const float*)d_in[9];
  const float* kv  = (const float*)d_in[10];
  const float* Wv  = (const float*)d_in[11];
  const float* vg  = (const float*)d_in[12];
  const float* vb  = (const float*)d_in[13];
  const float* vm  = (const float*)d_in[14];
  const float* vv  = (const float*)d_in[15];
  const float* pos = (const float*)d_in[16];
  const float* Wo  = (const float*)d_in[17];
  const float* bo  = (const float*)d_in[18];
  const float* ogm = (const float*)d_in[19];
  const float* obt = (const float*)d_in[20];
  const float* omn = (const float*)d_in[21];
  const float* ovr = (const float*)d_in[22];
  float* out = (float*)d_out;

  char* ws = (char*)d_ws;
  size_t off = 0;
  auto take = [&](size_t bytes) { char* p = ws + off; off += (bytes + 255) & ~(size_t)255; return p; };
  bf16*  wqkv = (bf16*) take((size_t)1024 * 256 * 2);
  float* bqkv = (float*)take(1024 * 4);
  bf16*  wo2  = (bf16*) take((size_t)256 * 512 * 2);
  float* bo2  = (float*)take(256 * 4);
  bf16*  xT   = (bf16*) take((size_t)B_ * S_ * C_ * 2);
  bf16*  qhb  = (bf16*) take((size_t)B_ * NH_ * S_ * DK_ * 2);
  bf16*  khb  = (bf16*) take((size_t)B_ * NH_ * S_ * DK_ * 2);
  bf16*  vTb  = (bf16*) take((size_t)B_ * NH_ * DV_ * S_ * 2);
  bf16*  ogb  = (bf16*) take((size_t)B_ * S_ * CV_ * 2);

  prep_kernel<<<dim3(1536), dim3(256), 0, stream>>>(Wq, qg, qb, qm, qv, Wk, kg, kb, km, kv,
                                                    Wv, vg, vb, vm, vv, Wo, bo, ogm, obt, omn, ovr,
                                                    wqkv, bqkv, wo2, bo2);
  xpose_kernel<<<dim3(16, 4, 16), dim3(256), 0, stream>>>(x, xT);
  qkv_gemm_kernel<<<dim3(8, 8, 16), dim3(256), 0, stream>>>(wqkv, bqkv, xT, qhb, khb, vTb);
  attn_kernel<<<dim3(8, 4, 16), dim3(512), 0, stream>>>(qhb, khb, vTb, pos, ogb);
  out_gemm_kernel<<<dim3(8, 4, 16), dim3(256), 0, stream>>>(wo2, bo2, ogb, out);
}

// Round 22
// 90.269 us; speedup vs baseline: 4.1176x; 4.1176x over previous
//
#include <hip/hip_runtime.h>

#define B_ 16
#define C_ 256
#define NH_ 8
#define DK_ 32
#define DV_ 64
#define S_ 1024
#define CV_ 512

typedef __bf16 bf16;
typedef bf16 bf16x4 __attribute__((ext_vector_type(4)));
typedef bf16 bf16x8 __attribute__((ext_vector_type(8)));
typedef float f32x4 __attribute__((ext_vector_type(4)));

constexpr float EPSV = 1e-5f;
constexpr float SCALE_ = 0.17677669529663687f;   // 32^-0.5
constexpr float LOG2E_ = 1.4426950408889634f;
constexpr float QSCALE_ = SCALE_ * LOG2E_;       // folded into Q weights
constexpr float BSCALE_ = (1.0f / SCALE_) * LOG2E_; // folded into bias table

// ---------------- prep: fold BN into weights, cast to bf16 ----------------
__global__ void prep_kernel(const float* __restrict__ Wq, const float* __restrict__ qg, const float* __restrict__ qb, const float* __restrict__ qm, const float* __restrict__ qv,
                            const float* __restrict__ Wk, const float* __restrict__ kg, const float* __restrict__ kb, const float* __restrict__ km, const float* __restrict__ kv,
                            const float* __restrict__ Wv, const float* __restrict__ vg, const float* __restrict__ vb, const float* __restrict__ vm, const float* __restrict__ vv,
                            const float* __restrict__ Wo, const float* __restrict__ bo, const float* __restrict__ og_, const float* __restrict__ ob_, const float* __restrict__ om_, const float* __restrict__ ov_,
                            bf16* __restrict__ wqkv, float* __restrict__ bqkv, bf16* __restrict__ wo2, float* __restrict__ bo2) {
  int idx = blockIdx.x * 256 + threadIdx.x;
  if (idx < 1024 * 256) {
    int o = idx >> 8, c = idx & 255;
    float w, g, v;
    if (o < 256)      { w = Wq[o * 256 + c];        g = qg[o];       v = qv[o]; }
    else if (o < 512) { w = Wk[(o - 256) * 256 + c]; g = kg[o - 256]; v = kv[o - 256]; }
    else              { w = Wv[(o - 512) * 256 + c]; g = vg[o - 512]; v = vv[o - 512]; }
    float inv = g * rsqrtf(v + EPSV);
    wqkv[idx] = (bf16)(w * inv);
    if (c == 0) {
      float bb, m;
      if (o < 256)      { bb = qb[o];       m = qm[o]; }
      else if (o < 512) { bb = kb[o - 256]; m = km[o - 256]; }
      else              { bb = vb[o - 512]; m = vm[o - 512]; }
      bqkv[o] = bb - m * inv;
    }
  } else {
    int j = idx - 1024 * 256;
    if (j < 256 * 512) {
      int co = j >> 9, cv = j & 511;
      float inv = og_[co] * rsqrtf(ov_[co] + EPSV);
      wo2[j] = (bf16)(Wo[j] * inv);
      if (cv == 0) bo2[co] = bo[co] * inv + ob_[co] - om_[co] * inv;
    }
  }
}

// ---------------- transpose x[b,c,s] f32 -> xT[b,s,c] bf16 (vectorized) ----------------
__global__ __launch_bounds__(256) void xpose_kernel(const float* __restrict__ x, bf16* __restrict__ xT) {
  __shared__ bf16 t[64][66];
  int b = blockIdx.z, c0 = blockIdx.y * 64, s0 = blockIdx.x * 64;
  const float* xp = x + ((size_t)b * C_ + c0) * S_ + s0;
#pragma unroll
  for (int p = 0; p < 4; ++p) {
    int q = p * 256 + threadIdx.x;          // 0..1023 quads
    int ci = q >> 4, si4 = (q & 15) * 4;
    float4 v = *(const float4*)(xp + (size_t)ci * S_ + si4);
    t[si4 + 0][ci] = (bf16)v.x;
    t[si4 + 1][ci] = (bf16)v.y;
    t[si4 + 2][ci] = (bf16)v.z;
    t[si4 + 3][ci] = (bf16)v.w;
  }
  __syncthreads();
  bf16* op = xT + ((size_t)b * S_ + s0) * C_ + c0;
#pragma unroll
  for (int p = 0; p < 4; ++p) {
    int q = p * 256 + threadIdx.x;
    int si = q >> 4, ci4 = (q & 15) * 4;
    bf16x4 pk;
#pragma unroll
    for (int e = 0; e < 4; ++e) pk[e] = t[si][ci4 + e];
    *(bf16x4*)(op + (size_t)si * C_ + ci4) = pk;
  }
}

// ---------------- fused QKV GEMM, m97 structure (proven round 14) ----------------
__device__ __forceinline__ void gload16(const void* g, void* l) {
  __builtin_amdgcn_global_load_lds((const __attribute__((address_space(1))) void*)g,
                                   (__attribute__((address_space(3))) void*)l, 16, 0, 0);
}

__global__ __launch_bounds__(256) void qkv_gemm_kernel(const bf16* __restrict__ wqkv, const float* __restrict__ bqkv,
                                                       const bf16* __restrict__ xT, bf16* __restrict__ qh,
                                                       bf16* __restrict__ kh, bf16* __restrict__ vT) {
  __shared__ bf16 alds[2][128 * 32];
  __shared__ bf16 blds[2][128 * 32];
  const int b = blockIdx.z;
  const int ob = blockIdx.y * 128, sb = blockIdx.x * 128;
  const int w = threadIdx.x >> 6, lane = threadIdx.x & 63;
  const int g = lane >> 4, lo = lane & 15;
  const int ow = (w >> 1) * 64, sw = (w & 1) * 64;

  const int r0 = threadIdx.x >> 2, c4 = threadIdx.x & 3;
  const int swz = (c4 ^ ((r0 >> 1) & 3)) * 8;
  const bf16* aS = wqkv + (size_t)(ob + r0) * C_ + swz;
  const bf16* bS = xT + ((size_t)b * S_ + sb + r0) * C_ + swz;
  const int ldst = threadIdx.x * 8;
  auto stage = [&](int buf, int kc) {
    gload16(aS + kc, &alds[buf][ldst]);
    gload16(aS + (size_t)64 * C_ + kc, &alds[buf][ldst + 2048]);
    gload16(bS + kc, &blds[buf][ldst]);
    gload16(bS + (size_t)64 * C_ + kc, &blds[buf][ldst + 2048]);
  };

  f32x4 acc[4][4] = {};

  stage(0, 0);
  __syncthreads();

  for (int step = 0; step < 8; ++step) {
    const int cur = step & 1;
    if (step < 7) stage(cur ^ 1, (step + 1) * 32);
    bf16x8 af[4], bfr[4];
    const int ch = (g ^ ((lo >> 1) & 3)) * 8;
#pragma unroll
    for (int i = 0; i < 4; ++i)
      af[i] = *(const bf16x8*)(&alds[cur][(ow + i * 16 + lo) * 32 + ch]);
#pragma unroll
    for (int j = 0; j < 4; ++j)
      bfr[j] = *(const bf16x8*)(&blds[cur][(sw + j * 16 + lo) * 32 + ch]);
#pragma unroll
    for (int i = 0; i < 4; ++i)
#pragma unroll
      for (int j = 0; j < 4; ++j)
        acc[i][j] = __builtin_amdgcn_mfma_f32_16x16x32_bf16(af[i], bfr[j], acc[i][j], 0, 0, 0);
    __syncthreads();
  }

#pragma unroll
  for (int i = 0; i < 4; ++i) {
    const int o0 = ob + ow + i * 16 + 4 * g;
    const bool isv = o0 >= 512;
    const bool isq = o0 < 256;
    float bias4[4];
#pragma unroll
    for (int r = 0; r < 4; ++r) bias4[r] = bqkv[o0 + r];
#pragma unroll
    for (int j = 0; j < 4; ++j) {
      const int s = sb + sw + j * 16 + lo;
      if (!isv) {
        const int n = (o0 >> 5) & 7;
        const int d0 = o0 & 31;
        bf16x4 pk;
#pragma unroll
        for (int r = 0; r < 4; ++r) {
          float v = acc[i][j][r] + bias4[r];
          pk[r] = (bf16)(isq ? v * QSCALE_ : v);
        }
        bf16* dst = (isq ? qh : kh) + (((size_t)b * NH_ + n) * S_ + s) * DK_ + d0;
        *(bf16x4*)dst = pk;
      } else {
        const int o2 = o0 - 512;
        const int n = o2 >> 6, dv0 = o2 & 63;
#pragma unroll
        for (int r = 0; r < 4; ++r)
          vT[(((size_t)b * NH_ + n) * DV_ + dv0 + r) * S_ + s] = (bf16)(acc[i][j][r] + bias4[r]);
      }
    }
  }
}

// ---------------- flash attention (proven: 32 q/wave, E4 bias in LDS, 47.9 us) ----------------
__global__ __launch_bounds__(512, 4) void attn_kernel(const bf16* __restrict__ qh, const bf16* __restrict__ kh,
                                                      const bf16* __restrict__ vT, const float* __restrict__ pos_emb,
                                                      bf16* __restrict__ og) {
  __shared__ f32x4 E4[32][64];
  __shared__ bf16 klds[2][64 * 32];
  __shared__ bf16 vlds[2][64 * 64];
  const int n = blockIdx.x, qt = blockIdx.y, b = blockIdx.z;
  const int w = threadIdx.x >> 6, lane = threadIdx.x & 63;
  const int g = lane >> 4, lo = lane & 15;
  const size_t bn = (size_t)b * NH_ + n;
  const bf16* __restrict__ kbase = kh + bn * (size_t)S_ * DK_;
  const bf16* __restrict__ vbase = vT + bn * (size_t)DV_ * S_;

  const int krow = (w & 3) * 16 + (lane >> 2), kslot = lane & 3;
  const int vrow = w * 8 + (lane >> 3), vslot = lane & 7;
  const bf16* ksrc0 = kbase + (size_t)krow * DK_ + ((kslot ^ ((krow >> 2) & 3)) * 8);
  const bf16* vsrc0 = vbase + (size_t)vrow * S_ + ((vslot ^ (vrow & 7)) * 8);
  auto stage = [&](int buf, int kt) {
    if (w < 4) gload16(ksrc0 + (size_t)kt * DK_, &klds[buf][(w & 3) * 512]);
    gload16(vsrc0 + kt, &vlds[buf][w * 512]);
  };

  stage(0, 0);

  for (int i = threadIdx.x; i < 32 * 64; i += 512) {
    const int dr = i >> 6, d = i & 63;
    f32x4 v;
#pragma unroll
    for (int j = 0; j < 4; ++j) {
      int dc = d - 28 - j;
      dc = dc < 0 ? -dc : dc;
      dc = dc > 31 ? 31 : dc;
      v[j] = pos_emb[(dr * 32 + dc) * NH_ + n] * BSCALE_;
    }
    E4[dr][d] = v;
  }

  const int qbase = qt * 256 + w * 32;
  const int q0 = qbase + lo, q1 = qbase + 16 + lo;
  const bf16x8 qf0 = *(const bf16x8*)(qh + (bn * S_ + q0) * DK_ + 8 * g);
  const bf16x8 qf1 = *(const bf16x8*)(qh + (bn * S_ + q1) * DK_ + 8 * g);
  const int qr = qbase >> 5;
  const int i00m = 12 + lo - 4 * g;   // i00 - 16, >= 0

  f32x4 acc[4][2] = {};
  f32x4 lac[2] = {};
  bf16x8 ones;
#pragma unroll
  for (int j = 0; j < 8; ++j) ones[j] = (bf16)1.0f;

  asm volatile("s_waitcnt vmcnt(0)" ::: "memory");
  __syncthreads();

  const f32x4* __restrict__ E4f = &E4[0][0];

  for (int it = 0; it < 16; ++it) {
    const int kt = it * 64;
    const int cur = it & 1;
    if (it < 15) stage(cur ^ 1, kt + 64);
    const bf16* kbuf = &klds[cur][0];
    const bf16* vbuf = &vlds[cur][0];

    int dq = qr - 2 * it;
    int dra = dq < 0 ? -dq : dq;
    int dqb = dq - 1;
    int drb = dqb < 0 ? -dqb : dqb;
    const f32x4* pa = E4f + dra * 64 + i00m;
    const f32x4* pbq = E4f + drb * 64 + i00m;
    const f32x4 W0a = pa[16], W0b = pbq[16];

    bf16x8 pb[2][2];
#pragma unroll
    for (int u = 0; u < 4; ++u) {
      const int row = u * 16 + lo;
      bf16x8 ka = *(const bf16x8*)(kbuf + row * 32 + ((8 * g) ^ (((row >> 2) & 3) << 3)));
      f32x4 c0, c1;
      if (u == 0)      { c0 = W0a;    c1 = pa[32]; }
      else if (u == 1) { c0 = pa[0];  c1 = W0a; }
      else if (u == 2) { c0 = W0b;    c1 = pbq[32]; }
      else             { c0 = pbq[0]; c1 = W0b; }
      f32x4 s0 = __builtin_amdgcn_mfma_f32_16x16x32_bf16(ka, qf0, c0, 0, 0, 0);
      f32x4 s1 = __builtin_amdgcn_mfma_f32_16x16x32_bf16(ka, qf1, c1, 0, 0, 0);
      const int cb = (u & 1) * 4;
      const int up = u >> 1;
#pragma unroll
      for (int r = 0; r < 4; ++r) {
        pb[0][up][cb + r] = (bf16)__builtin_amdgcn_exp2f(s0[r]);
        pb[1][up][cb + r] = (bf16)__builtin_amdgcn_exp2f(s1[r]);
      }
    }

    __builtin_amdgcn_s_setprio(1);
    lac[0] = __builtin_amdgcn_mfma_f32_16x16x32_bf16(ones, pb[0][0], lac[0], 0, 0, 0);
    lac[0] = __builtin_amdgcn_mfma_f32_16x16x32_bf16(ones, pb[0][1], lac[0], 0, 0, 0);
    lac[1] = __builtin_amdgcn_mfma_f32_16x16x32_bf16(ones, pb[1][0], lac[1], 0, 0, 0);
    lac[1] = __builtin_amdgcn_mfma_f32_16x16x32_bf16(ones, pb[1][1], lac[1], 0, 0, 0);

#pragma unroll
    for (int t = 0; t < 4; ++t) {
      const int row = t * 16 + lo;
      const int rsw = row & 7;
      const bf16* vrow_p = vbuf + row * 64 + 4 * (g & 1);
      const int ghalf = g >> 1;
#pragma unroll
      for (int up = 0; up < 2; ++up) {
        bf16x4 a0 = *(const bf16x4*)(vrow_p + ((((4 * up + 0) + ghalf) ^ rsw) << 3));
        bf16x4 a1 = *(const bf16x4*)(vrow_p + ((((4 * up + 2) + ghalf) ^ rsw) << 3));
        bf16x8 va = __builtin_shufflevector(a0, a1, 0, 1, 2, 3, 4, 5, 6, 7);
        acc[t][0] = __builtin_amdgcn_mfma_f32_16x16x32_bf16(va, pb[0][up], acc[t][0], 0, 0, 0);
        acc[t][1] = __builtin_amdgcn_mfma_f32_16x16x32_bf16(va, pb[1][up], acc[t][1], 0, 0, 0);
      }
    }
    __builtin_amdgcn_s_setprio(0);

    asm volatile("s_waitcnt vmcnt(0)" ::: "memory");
    __syncthreads();
  }

#pragma unroll
  for (int h = 0; h < 2; ++h) {
    const float rinv = __builtin_amdgcn_rcpf(lac[h][0]);
    const int qx = qbase + 16 * h + lo;
    bf16* op = og + ((size_t)b * S_ + qx) * CV_ + n * DV_;
#pragma unroll
    for (int t = 0; t < 4; ++t) {
      bf16x4 pk;
#pragma unroll
      for (int r = 0; r < 4; ++r) {
        float xo = acc[t][h][r] * rinv;
        pk[r] = (bf16)(0.5f * xo * (1.f + erff(xo * 0.70710678118654752f)));
      }
      *(bf16x4*)(op + t * 16 + 4 * g) = pk;
    }
  }
}

// ---------------- output GEMM, m97 structure (proven round 15) ----------------
__global__ __launch_bounds__(256) void out_gemm_kernel(const bf16* __restrict__ wo2, const float* __restrict__ bo2,
                                                       const bf16* __restrict__ og, float* __restrict__ out) {
  __shared__ bf16 alds[2][64 * 32];
  __shared__ bf16 blds[2][128 * 32];
  const int b = blockIdx.z;
  const int cb = blockIdx.y * 64, sb = blockIdx.x * 128;
  const int w = threadIdx.x >> 6, lane = threadIdx.x & 63;
  const int g = lane >> 4, lo = lane & 15;
  const int cw = (w >> 1) * 32, sw = (w & 1) * 64;

  const int r0 = threadIdx.x >> 2, c4 = threadIdx.x & 3;
  const int swz = (c4 ^ ((r0 >> 1) & 3)) * 8;
  const bf16* aS = wo2 + (size_t)(cb + r0) * CV_ + swz;
  const bf16* bS = og + ((size_t)b * S_ + sb + r0) * CV_ + swz;
  const int ldst = threadIdx.x * 8;
  auto stage = [&](int buf, int kc) {
    gload16(aS + kc, &alds[buf][ldst]);
    gload16(bS + kc, &blds[buf][ldst]);
    gload16(bS + (size_t)64 * CV_ + kc, &blds[buf][ldst + 2048]);
  };

  f32x4 acc[2][4] = {};

  stage(0, 0);
  __syncthreads();

  for (int step = 0; step < 16; ++step) {
    const int cur = step & 1;
    if (step < 15) stage(cur ^ 1, (step + 1) * 32);
    bf16x8 af[2], bfr[4];
    const int ch = (g ^ ((lo >> 1) & 3)) * 8;
#pragma unroll
    for (int i = 0; i < 2; ++i)
      af[i] = *(const bf16x8*)(&alds[cur][(cw + i * 16 + lo) * 32 + ch]);
#pragma unroll
    for (int j = 0; j < 4; ++j)
      bfr[j] = *(const bf16x8*)(&blds[cur][(sw + j * 16 + lo) * 32 + ch]);
#pragma unroll
    for (int i = 0; i < 2; ++i)
#pragma unroll
      for (int j = 0; j < 4; ++j)
        acc[i][j] = __builtin_amdgcn_mfma_f32_16x16x32_bf16(af[i], bfr[j], acc[i][j], 0, 0, 0);
    __syncthreads();
  }

#pragma unroll
  for (int i = 0; i < 2; ++i) {
    const int c0 = cb + cw + i * 16 + 4 * g;
    float bias4[4];
#pragma unroll
    for (int r = 0; r < 4; ++r) bias4[r] = bo2[c0 + r];
#pragma unroll
    for (int j = 0; j < 4; ++j) {
      const int s = sb + sw + j * 16 + lo;
#pragma unroll
      for (int r = 0; r < 4; ++r)
        out[((size_t)b * C_ + c0 + r) * S_ + s] = acc[i][j][r] + bias4[r];
    }
  }
}

extern "C" void kernel_launch(void* const* d_in, const int* in_sizes, int n_in,
                              void* d_out, int out_size, void* d_ws, size_t ws_size,
                              hipStream_t stream) {
  (void)in_sizes; (void)n_in; (void)out_size; (void)ws_size;
  const float* x   = (const float*)d_in[0];
  const float* Wq  = (const float*)d_in[1];
  const float* qg  = (const float*)d_in[2];
  const float* qb  = (const float*)d_in[3];
  const float* qm  = (const float*)d_in[4];
  const float* qv  = (const float*)d_in[5];
  const float* Wk  = (const float*)d_in[6];
  const float* kg  = (const float*)d_in[7];
  const float* kb  = (const float*)d_in[8];
  const float* km  = (const float*)d_in[9];
  const float* kv  = (const float*)d_in[10];
  const float* Wv  = (const float*)d_in[11];
  const float* vg  = (const float*)d_in[12];
  const float* vb  = (const float*)d_in[13];
  const float* vm  = (const float*)d_in[14];
  const float* vv  = (const float*)d_in[15];
  const float* pos = (const float*)d_in[16];
  const float* Wo  = (const float*)d_in[17];
  const float* bo  = (const float*)d_in[18];
  const float* ogm = (const float*)d_in[19];
  const float* obt = (const float*)d_in[20];
  const float* omn = (const float*)d_in[21];
  const float* ovr = (const float*)d_in[22];
  float* out = (float*)d_out;

  char* ws = (char*)d_ws;
  size_t off = 0;
  auto take = [&](size_t bytes) { char* p = ws + off; off += (bytes + 255) & ~(size_t)255; return p; };
  bf16*  wqkv = (bf16*) take((size_t)1024 * 256 * 2);
  float* bqkv = (float*)take(1024 * 4);
  bf16*  wo2  = (bf16*) take((size_t)256 * 512 * 2);
  float* bo2  = (float*)take(256 * 4);
  bf16*  xT   = (bf16*) take((size_t)B_ * S_ * C_ * 2);
  bf16*  qhb  = (bf16*) take((size_t)B_ * NH_ * S_ * DK_ * 2);
  bf16*  khb  = (bf16*) take((size_t)B_ * NH_ * S_ * DK_ * 2);
  bf16*  vTb  = (bf16*) take((size_t)B_ * NH_ * DV_ * S_ * 2);
  bf16*  ogb  = (bf16*) take((size_t)B_ * S_ * CV_ * 2);

  prep_kernel<<<dim3(1536), dim3(256), 0, stream>>>(Wq, qg, qb, qm, qv, Wk, kg, kb, km, kv,
                                                    Wv, vg, vb, vm, vv, Wo, bo, ogm, obt, omn, ovr,
                                                    wqkv, bqkv, wo2, bo2);
  xpose_kernel<<<dim3(16, 4, 16), dim3(256), 0, stream>>>(x, xT);
  qkv_gemm_kernel<<<dim3(8, 8, 16), dim3(256), 0, stream>>>(wqkv, bqkv, xT, qhb, khb, vTb);
  attn_kernel<<<dim3(8, 4, 16), dim3(512), 0, stream>>>(qhb, khb, vTb, pos, ogb);
  out_gemm_kernel<<<dim3(8, 4, 16), dim3(256), 0, stream>>>(wo2, bo2, ogb, out);
}